// Round 1
// 365.906 us; speedup vs baseline: 1.0752x; 1.0752x over previous
//
#include <hip/hip_runtime.h>

#define NEG_SLOPE 0.2f
#define BK_LOG 9
#define BK_NODES (1 << BK_LOG)       // 512 nodes per bucket
#define TILE_EPT 24
#define TILE_E (256 * TILE_EPT)      // 6144 edges per partition tile

typedef __attribute__((ext_vector_type(8))) short bf8_t;   // 8 bf16 (4 VGPRs)
typedef __attribute__((ext_vector_type(4))) float f32x4;

__device__ __forceinline__ float leaky(float v) { return v > 0.0f ? v : NEG_SLOPE * v; }

// fp32 -> bf16 (RNE) bit tricks; inputs are finite (no NaN handling needed)
__device__ __forceinline__ unsigned short f2bf(float f) {
    unsigned u = __float_as_uint(f);
    u += 0x7fffu + ((u >> 16) & 1u);
    return (unsigned short)(u >> 16);
}
__device__ __forceinline__ float bf2f(unsigned short h) {
    return __uint_as_float(((unsigned)h) << 16);
}

// exclusive scan of one value per thread across a 256-thread block
__device__ __forceinline__ int scan256_excl(int v, int* tmp) {
    int t = threadIdx.x;
    tmp[t] = v;
    __syncthreads();
    for (int d = 1; d < 256; d <<= 1) {
        int x = (t >= d) ? tmp[t - d] : 0;
        __syncthreads();
        tmp[t] += x;
        __syncthreads();
    }
    int r = tmp[t] - v;
    __syncthreads();
    return r;
}

// ---------------- edge partition (counting sort by dst-bucket) ----------------

__global__ __launch_bounds__(256) void k_bzero(int* __restrict__ bcnt) {
    bcnt[threadIdx.x] = 0;
}

__global__ __launch_bounds__(256) void k_bcount(const int* __restrict__ edst,
                                                int* __restrict__ bcnt, int E) {
    __shared__ int th[256];
    int t = threadIdx.x;
    th[t] = 0;
    __syncthreads();
    int base = blockIdx.x * TILE_E;
#pragma unroll
    for (int k = 0; k < TILE_EPT; ++k) {
        int e = base + t + k * 256;
        if (e < E) atomicAdd(&th[edst[e] >> BK_LOG], 1);
    }
    __syncthreads();
    if (th[t]) atomicAdd(&bcnt[t], th[t]);
}

__global__ __launch_bounds__(256) void k_bscan(const int* __restrict__ bcnt,
                                               int* __restrict__ bbase,
                                               int* __restrict__ bcur,
                                               int* __restrict__ off, int N, int E) {
    __shared__ int tmp[256];
    int t = threadIdx.x;
    int ex = scan256_excl(bcnt[t], tmp);
    bbase[t] = ex;
    bcur[t]  = ex;
    if (t == 0) { bbase[256] = E; off[N] = E; }
}

__global__ __launch_bounds__(256) void k_bplace(const int* __restrict__ esrc,
                                                const int* __restrict__ edst,
                                                int* __restrict__ bcur,
                                                int2* __restrict__ pairs, int E) {
    __shared__ int2 sp[TILE_E];
    __shared__ int th[256], tx[256], rb[256], tmp[256];
    int t = threadIdx.x;
    th[t] = 0;
    __syncthreads();
    int base = blockIdx.x * TILE_E;
    int tot  = min(TILE_E, E - base);
#pragma unroll
    for (int k = 0; k < TILE_EPT; ++k) {
        int e = base + t + k * 256;
        if (e < E) atomicAdd(&th[edst[e] >> BK_LOG], 1);
    }
    __syncthreads();
    int cnt = th[t];
    tx[t] = scan256_excl(cnt, tmp);
    rb[t] = atomicAdd(&bcur[t], cnt);
    th[t] = 0;
    __syncthreads();
#pragma unroll
    for (int k = 0; k < TILE_EPT; ++k) {
        int e = base + t + k * 256;
        if (e < E) {
            int s = esrc[e], d = edst[e];
            int b = d >> BK_LOG;
            int r = atomicAdd(&th[b], 1);
            sp[tx[b] + r] = make_int2(s, d);
        }
    }
    __syncthreads();
    for (int i = t; i < tot; i += 256) {
        int2 p = sp[i];
        int  b = p.y >> BK_LOG;
        pairs[rb[b] + (i - tx[b])] = p;
    }
}

__global__ __launch_bounds__(256) void k_csr(const int* __restrict__ bbase,
                                             const int2* __restrict__ pairs,
                                             int* __restrict__ off,
                                             int* __restrict__ csr, int N) {
    __shared__ int lh[BK_NODES], lx[BK_NODES];
    int b = blockIdx.x, t = threadIdx.x;
    int lo = bbase[b], hi = bbase[b + 1];
    int node0 = b << BK_LOG;
    lh[t] = 0; lh[t + 256] = 0;
    __syncthreads();
    for (int j = lo + t; j < hi; j += 256)
        atomicAdd(&lh[pairs[j].y - node0], 1);
    __syncthreads();
    lx[t] = lh[t]; lx[t + 256] = lh[t + 256];
    __syncthreads();
    for (int d = 1; d < BK_NODES; d <<= 1) {
        int i1 = t + 256;
        int x0 = (t  >= d) ? lx[t  - d] : 0;
        int x1 = (i1 >= d) ? lx[i1 - d] : 0;
        __syncthreads();
        lx[t] += x0; lx[i1] += x1;
        __syncthreads();
    }
    lx[t] -= lh[t]; lx[t + 256] -= lh[t + 256];
    if (node0 + t       < N) off[node0 + t]       = lo + lx[t];
    if (node0 + t + 256 < N) off[node0 + t + 256] = lo + lx[t + 256];
    lh[t] = 0; lh[t + 256] = 0;
    __syncthreads();
    for (int j = lo + t; j < hi; j += 256) {
        int2 p  = pairs[j];
        int  li = p.y - node0;
        int  r  = atomicAdd(&lh[li], 1);
        csr[lo + lx[li] + r] = p.x;
    }
}

// ---------------- MFMA GEMM (split-bf16, fp32-class accuracy) ----------------
// W [K][32] -> pre-swizzled B fragments in MFMA lane order:
//   wf[((kt*2+nt)*64 + lane)*8 + j] holds W[kt*32 + (lane>>4)*8 + j][nt*16 + (lane&15)]
__global__ __launch_bounds__(256) void k_wsplit(const float* __restrict__ W,
                                                unsigned short* __restrict__ wh,
                                                unsigned short* __restrict__ wl,
                                                int K) {
    int idx = blockIdx.x * 256 + threadIdx.x;
    int KT = K >> 5;
    if (idx >= KT * 128) return;       // KT*2*64 fragments-of-8
    int lane = idx & 63;
    int nt = (idx >> 6) & 1;
    int kt = idx >> 7;
    int q = lane >> 4, c = lane & 15;
#pragma unroll
    for (int j = 0; j < 8; ++j) {
        int k = kt * 32 + q * 8 + j;
        int n = nt * 16 + c;
        float w = W[k * 32 + n];
        unsigned short hi = f2bf(w);
        wh[idx * 8 + j] = hi;
        wl[idx * 8 + j] = f2bf(w - bf2f(hi));
    }
}

// One wave per 16-row M-tile. x split to (hi,lo) bf16 in-flight; 3 MFMA passes.
// ATT: also alpha_s/alpha_d via cross-lane reduce.  !ATT: adds bias (final gemm).
template <int FIN, bool ATT>
__global__ __launch_bounds__(256) void gemm_mfma(
    const float* __restrict__ x,
    const unsigned short* __restrict__ wh, const unsigned short* __restrict__ wl,
    const float* __restrict__ a_s, const float* __restrict__ a_d,
    const float* __restrict__ bias,
    float* __restrict__ h, float* __restrict__ alpha_s,
    float* __restrict__ alpha_d, int N)
{
    constexpr int KT = FIN / 32;
    int lane = threadIdx.x & 63;
    int mt   = blockIdx.x * 4 + (threadIdx.x >> 6);
    int m0   = mt * 16;
    if (m0 >= N) return;
    int q = lane >> 4, c = lane & 15;

    // B fragments (identical for all waves; L1/L2-broadcast)
    bf8_t Bh[KT][2], Bl[KT][2];
#pragma unroll
    for (int kt = 0; kt < KT; ++kt)
#pragma unroll
        for (int nt = 0; nt < 2; ++nt) {
            Bh[kt][nt] = *(const bf8_t*)(wh + ((size_t)(kt * 2 + nt) * 64 + lane) * 8);
            Bl[kt][nt] = *(const bf8_t*)(wl + ((size_t)(kt * 2 + nt) * 64 + lane) * 8);
        }

    // A fragments: row = m0 + c, k = kt*32 + q*8 + j  (coalesced 32 B/lane)
    int rowa = m0 + c;
    if (rowa >= N) rowa = N - 1;
    const float* xr = x + (size_t)rowa * FIN;
    bf8_t Ah[KT], Al[KT];
#pragma unroll
    for (int kt = 0; kt < KT; ++kt) {
        f32x4 v0 = *(const f32x4*)(xr + kt * 32 + q * 8);
        f32x4 v1 = *(const f32x4*)(xr + kt * 32 + q * 8 + 4);
#pragma unroll
        for (int j = 0; j < 8; ++j) {
            float f = (j < 4) ? v0[j] : v1[j - 4];
            unsigned short hi = f2bf(f);
            Ah[kt][j] = (short)hi;
            Al[kt][j] = (short)f2bf(f - bf2f(hi));
        }
    }

    f32x4 acc0 = {0.f, 0.f, 0.f, 0.f}, acc1 = {0.f, 0.f, 0.f, 0.f};
#pragma unroll
    for (int kt = 0; kt < KT; ++kt) {
        acc0 = __builtin_amdgcn_mfma_f32_16x16x32_bf16(Ah[kt], Bh[kt][0], acc0, 0, 0, 0);
        acc1 = __builtin_amdgcn_mfma_f32_16x16x32_bf16(Ah[kt], Bh[kt][1], acc1, 0, 0, 0);
        acc0 = __builtin_amdgcn_mfma_f32_16x16x32_bf16(Al[kt], Bh[kt][0], acc0, 0, 0, 0);
        acc1 = __builtin_amdgcn_mfma_f32_16x16x32_bf16(Al[kt], Bh[kt][1], acc1, 0, 0, 0);
        acc0 = __builtin_amdgcn_mfma_f32_16x16x32_bf16(Ah[kt], Bl[kt][0], acc0, 0, 0, 0);
        acc1 = __builtin_amdgcn_mfma_f32_16x16x32_bf16(Ah[kt], Bl[kt][1], acc1, 0, 0, 0);
    }

    // D layout: col = lane&15, row = q*4 + reg
#pragma unroll
    for (int reg = 0; reg < 4; ++reg) {
        int r = m0 + q * 4 + reg;
        if (r < N) {
            float v0s = acc0[reg], v1s = acc1[reg];
            if (!ATT) { v0s += bias[c]; v1s += bias[c + 16]; }
            h[(size_t)r * 32 + c]      = v0s;
            h[(size_t)r * 32 + 16 + c] = v1s;
        }
    }
    if (ATT) {
        float as0 = a_s[c], as1 = a_s[c + 16];
        float ad0 = a_d[c], ad1 = a_d[c + 16];
#pragma unroll
        for (int reg = 0; reg < 4; ++reg) {
            float ps = acc0[reg] * as0 + acc1[reg] * as1;
            float pd = acc0[reg] * ad0 + acc1[reg] * ad1;
#pragma unroll
            for (int msk = 8; msk >= 1; msk >>= 1) {
                ps += __shfl_xor(ps, msk);
                pd += __shfl_xor(pd, msk);
            }
            int r = m0 + q * 4 + reg;
            if (c == 0 && r < N) {
                alpha_s[r] = ps;
                alpha_d[r] = pd;
            }
        }
    }
}

// ---------------- aggregation ----------------
// 8 lanes per node, float4 features per lane. Per-edge weight computed ONCE by
// the chunk-owning lane, broadcast via width-8 shuffle (was: 32x redundant
// expf/leaky/alpha-gather per edge -> VALU-bound at 68% busy).
__global__ __launch_bounds__(256) void fused_agg(
    const int* __restrict__ csr, const int* __restrict__ off,
    const float* __restrict__ alpha_s, const float* __restrict__ alpha_d,
    const float* __restrict__ h, const float* __restrict__ bias,
    float* __restrict__ out, int N)
{
    int t = blockIdx.x * 256 + threadIdx.x;
    int i = t >> 3, q = t & 7;          // node i, feature quad q (k = q*4..q*4+3)
    if (i >= N) return;
    int s0 = off[i], s1 = off[i + 1];
    float ad = alpha_d[i];

    const float* hq = h + q * 4;        // per-lane feature base

    // self loop
    float w   = __expf(leaky(alpha_s[i] + ad));
    float den = w;
    f32x4 hv  = *(const f32x4*)(hq + (size_t)i * 32);
    f32x4 acc;
    acc[0] = w * hv[0]; acc[1] = w * hv[1]; acc[2] = w * hv[2]; acc[3] = w * hv[3];

    int j = s0;
    // full chunks of 8 edges: lane q owns edge j+q, computes its weight once
    for (; j + 8 <= s1; j += 8) {
        int   c  = csr[j + q];
        float wv = __expf(leaky(alpha_s[c] + ad));
        int   co = c << 5;              // float offset of row c
#pragma unroll
        for (int e = 0; e < 8; ++e) {
            int   ce = __shfl(co, e, 8);
            float we = __shfl(wv, e, 8);
            f32x4 hg = *(const f32x4*)(hq + ce);
            den += we;
            acc[0] += we * hg[0]; acc[1] += we * hg[1];
            acc[2] += we * hg[2]; acc[3] += we * hg[3];
        }
    }
    // tail (< 8 edges)
    int rem = s1 - j;
    if (rem > 0) {
        int c = 0; float wv = 0.0f;
        if (q < rem) {
            c  = csr[j + q];
            wv = __expf(leaky(alpha_s[c] + ad));
        }
        int co = c << 5;
        for (int e = 0; e < rem; ++e) {
            int   ce = __shfl(co, e, 8);
            float we = __shfl(wv, e, 8);
            f32x4 hg = *(const f32x4*)(hq + ce);
            den += we;
            acc[0] += we * hg[0]; acc[1] += we * hg[1];
            acc[2] += we * hg[2]; acc[3] += we * hg[3];
        }
    }

    float inv = 1.0f / den;
    f32x4 b4  = *(const f32x4*)(bias + q * 4);
    f32x4 r;
    r[0] = fmaxf(acc[0] * inv + b4[0], 0.0f);
    r[1] = fmaxf(acc[1] * inv + b4[1], 0.0f);
    r[2] = fmaxf(acc[2] * inv + b4[2], 0.0f);
    r[3] = fmaxf(acc[3] * inv + b4[3], 0.0f);
    *(f32x4*)(out + (size_t)i * 32 + q * 4) = r;
}

extern "C" void kernel_launch(void* const* d_in, const int* in_sizes, int n_in,
                              void* d_out, int out_size, void* d_ws, size_t ws_size,
                              hipStream_t stream)
{
    const float* x   = (const float*)d_in[0];
    const int*   ei  = (const int*)d_in[1];
    const float* W1  = (const float*)d_in[2];
    const float* a1s = (const float*)d_in[3];
    const float* a1d = (const float*)d_in[4];
    const float* b1  = (const float*)d_in[5];
    const float* W2  = (const float*)d_in[6];
    const float* a2s = (const float*)d_in[7];
    const float* a2d = (const float*)d_in[8];
    const float* b2  = (const float*)d_in[9];
    const float* Wf  = (const float*)d_in[10];
    const float* bf  = (const float*)d_in[11];

    const int N = in_sizes[0] / 128;
    const int E = in_sizes[1] / 2;
    const int* esrc = ei;
    const int* edst = ei + E;
    const int B1 = (N + BK_NODES - 1) >> BK_LOG;

    // Workspace (4B units): h1 32N | h2 32N | alpha_s N | alpha_d N |
    //   off N+1 | csr E | bcnt 256 | bbase 257 | bcur 256 | wfrag arrays
    float* ws = (float*)d_ws;
    float* h1      = ws;
    float* h2      = h1 + (size_t)N * 32;
    float* alpha_s = h2 + (size_t)N * 32;
    float* alpha_d = alpha_s + N;
    int*   off     = (int*)(alpha_d + N);
    int*   csr     = off + (N + 1);
    int*   bcnt    = csr + E;
    int*   bbase   = bcnt + 256;
    int*   bcur    = bbase + 257;
    unsigned short* wfb =
        (unsigned short*)(((uintptr_t)(bcur + 256) + 15) & ~(uintptr_t)15);
    unsigned short* wh1 = wfb;            // 4096 each for K=128
    unsigned short* wl1 = wh1 + 4096;
    unsigned short* wh2 = wl1 + 4096;     // 1024 each for K=32
    unsigned short* wl2 = wh2 + 1024;
    unsigned short* whf = wl2 + 1024;
    unsigned short* wlf = whf + 1024;
    // pairs (E int2) aliases h1+h2 (build completes before h is live)
    int2* pairs = ((size_t)2 * E <= (size_t)64 * N)
                      ? (int2*)h1
                      : (int2*)(wlf + 1024);

    const int nb_agg  = (N * 8 + 255) / 256;
    const int nb_tile = (E + TILE_E - 1) / TILE_E;
    const int nb_gemm = ((N + 15) / 16 + 3) / 4;

    // ---- weight fragment precompute ----
    k_wsplit<<<2, 256, 0, stream>>>(W1, wh1, wl1, 128);
    k_wsplit<<<1, 256, 0, stream>>>(W2, wh2, wl2, 32);
    k_wsplit<<<1, 256, 0, stream>>>(Wf, whf, wlf, 32);

    // ---- CSR build ----
    k_bzero  <<<1, 256, 0, stream>>>(bcnt);
    k_bcount <<<nb_tile, 256, 0, stream>>>(edst, bcnt, E);
    k_bscan  <<<1, 256, 0, stream>>>(bcnt, bbase, bcur, off, N, E);
    k_bplace <<<nb_tile, 256, 0, stream>>>(esrc, edst, bcur, pairs, E);
    k_csr    <<<B1, 256, 0, stream>>>(bbase, pairs, off, csr, N);

    // ---- layer 1 ----
    gemm_mfma<128, true><<<nb_gemm, 256, 0, stream>>>(
        x, wh1, wl1, a1s, a1d, nullptr, h1, alpha_s, alpha_d, N);
    fused_agg<<<nb_agg, 256, 0, stream>>>(csr, off, alpha_s, alpha_d, h1, b1, h2, N);

    // ---- layer 2 ----
    gemm_mfma<32, true><<<nb_gemm, 256, 0, stream>>>(
        h2, wh2, wl2, a2s, a2d, nullptr, h1, alpha_s, alpha_d, N);
    fused_agg<<<nb_agg, 256, 0, stream>>>(csr, off, alpha_s, alpha_d, h1, b2, h2, N);

    // ---- final linear ----
    gemm_mfma<32, false><<<nb_gemm, 256, 0, stream>>>(
        h2, whf, wlf, nullptr, nullptr, bf, (float*)d_out, nullptr, nullptr, N);
}

// Round 3
// 353.332 us; speedup vs baseline: 1.1134x; 1.0356x over previous
//
#include <hip/hip_runtime.h>

#define NEG_SLOPE 0.2f
#define BK_LOG 9
#define BK_NODES (1 << BK_LOG)       // 512 nodes per bucket
#define TILE_EPT 24
#define TILE_E (256 * TILE_EPT)      // 6144 edges per partition tile

typedef __attribute__((ext_vector_type(8))) short bf8_t;   // 8 bf16 (4 VGPRs)
typedef __attribute__((ext_vector_type(4))) float f32x4;

__device__ __forceinline__ float leaky(float v) { return v > 0.0f ? v : NEG_SLOPE * v; }

// fp32 -> bf16 (RNE) bit tricks; inputs are finite (no NaN handling needed)
__device__ __forceinline__ unsigned short f2bf(float f) {
    unsigned u = __float_as_uint(f);
    u += 0x7fffu + ((u >> 16) & 1u);
    return (unsigned short)(u >> 16);
}
__device__ __forceinline__ float bf2f(unsigned short h) {
    return __uint_as_float(((unsigned)h) << 16);
}

// exclusive scan of one value per thread across a 256-thread block
__device__ __forceinline__ int scan256_excl(int v, int* tmp) {
    int t = threadIdx.x;
    tmp[t] = v;
    __syncthreads();
    for (int d = 1; d < 256; d <<= 1) {
        int x = (t >= d) ? tmp[t - d] : 0;
        __syncthreads();
        tmp[t] += x;
        __syncthreads();
    }
    int r = tmp[t] - v;
    __syncthreads();
    return r;
}

// ---------------- edge partition (counting sort by dst-bucket) ----------------

__global__ __launch_bounds__(256) void k_bzero(int* __restrict__ bcnt) {
    bcnt[threadIdx.x] = 0;
}

__global__ __launch_bounds__(256) void k_bcount(const int* __restrict__ edst,
                                                int* __restrict__ bcnt, int E) {
    __shared__ int th[256];
    int t = threadIdx.x;
    th[t] = 0;
    __syncthreads();
    int base = blockIdx.x * TILE_E;
#pragma unroll
    for (int k = 0; k < TILE_EPT; ++k) {
        int e = base + t + k * 256;
        if (e < E) atomicAdd(&th[edst[e] >> BK_LOG], 1);
    }
    __syncthreads();
    if (th[t]) atomicAdd(&bcnt[t], th[t]);
}

__global__ __launch_bounds__(256) void k_bscan(const int* __restrict__ bcnt,
                                               int* __restrict__ bbase,
                                               int* __restrict__ bcur,
                                               int* __restrict__ off, int N, int E) {
    __shared__ int tmp[256];
    int t = threadIdx.x;
    int ex = scan256_excl(bcnt[t], tmp);
    bbase[t] = ex;
    bcur[t]  = ex;
    if (t == 0) { bbase[256] = E; off[N] = E; }
}

// pairs packed: (src << BK_LOG) | (dst & (BK_NODES-1)); bucket implied by position
__global__ __launch_bounds__(256) void k_bplace(const int* __restrict__ esrc,
                                                const int* __restrict__ edst,
                                                int* __restrict__ bcur,
                                                unsigned* __restrict__ pairs, int E) {
    __shared__ int2 sp[TILE_E];
    __shared__ int th[256], tx[256], rb[256], tmp[256];
    int t = threadIdx.x;
    th[t] = 0;
    __syncthreads();
    int base = blockIdx.x * TILE_E;
    int tot  = min(TILE_E, E - base);
#pragma unroll
    for (int k = 0; k < TILE_EPT; ++k) {
        int e = base + t + k * 256;
        if (e < E) atomicAdd(&th[edst[e] >> BK_LOG], 1);
    }
    __syncthreads();
    int cnt = th[t];
    tx[t] = scan256_excl(cnt, tmp);
    rb[t] = atomicAdd(&bcur[t], cnt);
    th[t] = 0;
    __syncthreads();
#pragma unroll
    for (int k = 0; k < TILE_EPT; ++k) {
        int e = base + t + k * 256;
        if (e < E) {
            int s = esrc[e], d = edst[e];
            int b = d >> BK_LOG;
            int r = atomicAdd(&th[b], 1);
            sp[tx[b] + r] = make_int2(s, d);
        }
    }
    __syncthreads();
    for (int i = t; i < tot; i += 256) {
        int2 p = sp[i];
        int  b = p.y >> BK_LOG;
        pairs[rb[b] + (i - tx[b])] =
            ((unsigned)p.x << BK_LOG) | (unsigned)(p.y & (BK_NODES - 1));
    }
}

// 512 threads: one bucket (512 nodes) per block, 1 node per thread
__global__ __launch_bounds__(512) void k_csr(const int* __restrict__ bbase,
                                             const unsigned* __restrict__ pairs,
                                             int* __restrict__ off,
                                             int* __restrict__ csr, int N) {
    __shared__ int lh[BK_NODES], lx[BK_NODES];
    int b = blockIdx.x, t = threadIdx.x;
    int lo = bbase[b], hi = bbase[b + 1];
    int node0 = b << BK_LOG;
    lh[t] = 0;
    __syncthreads();
    for (int j = lo + t; j < hi; j += 512)
        atomicAdd(&lh[pairs[j] & (BK_NODES - 1)], 1);
    __syncthreads();
    lx[t] = lh[t];
    __syncthreads();
    for (int d = 1; d < BK_NODES; d <<= 1) {
        int x0 = (t >= d) ? lx[t - d] : 0;
        __syncthreads();
        lx[t] += x0;
        __syncthreads();
    }
    lx[t] -= lh[t];
    if (node0 + t < N) off[node0 + t] = lo + lx[t];
    lh[t] = 0;
    __syncthreads();
    for (int j = lo + t; j < hi; j += 512) {
        unsigned p  = pairs[j];
        int      li = p & (BK_NODES - 1);
        int      r  = atomicAdd(&lh[li], 1);
        csr[lo + lx[li] + r] = (int)(p >> BK_LOG);
    }
}

// ---------------- MFMA GEMM (split-bf16, fp32-class accuracy) ----------------
// W [K][32] -> pre-swizzled B fragments in MFMA lane order:
//   wf[((kt*2+nt)*64 + lane)*8 + j] holds W[kt*32 + (lane>>4)*8 + j][nt*16 + (lane&15)]
__global__ __launch_bounds__(256) void k_wsplit(const float* __restrict__ W,
                                                unsigned short* __restrict__ wh,
                                                unsigned short* __restrict__ wl,
                                                int K) {
    int idx = blockIdx.x * 256 + threadIdx.x;
    int KT = K >> 5;
    if (idx >= KT * 128) return;       // KT*2*64 fragments-of-8
    int lane = idx & 63;
    int nt = (idx >> 6) & 1;
    int kt = idx >> 7;
    int q = lane >> 4, c = lane & 15;
#pragma unroll
    for (int j = 0; j < 8; ++j) {
        int k = kt * 32 + q * 8 + j;
        int n = nt * 16 + c;
        float w = W[k * 32 + n];
        unsigned short hi = f2bf(w);
        wh[idx * 8 + j] = hi;
        wl[idx * 8 + j] = f2bf(w - bf2f(hi));
    }
}

// One wave per 16-row M-tile. x split to (hi,lo) bf16 in-flight; 3 MFMA passes.
// ATT: also alpha_s/alpha_d via cross-lane reduce.  !ATT: adds bias (final gemm).
template <int FIN, bool ATT>
__global__ __launch_bounds__(256) void gemm_mfma(
    const float* __restrict__ x,
    const unsigned short* __restrict__ wh, const unsigned short* __restrict__ wl,
    const float* __restrict__ a_s, const float* __restrict__ a_d,
    const float* __restrict__ bias,
    float* __restrict__ h, float* __restrict__ alpha_s,
    float* __restrict__ alpha_d, int N)
{
    constexpr int KT = FIN / 32;
    int lane = threadIdx.x & 63;
    int mt   = blockIdx.x * 4 + (threadIdx.x >> 6);
    int m0   = mt * 16;
    if (m0 >= N) return;
    int q = lane >> 4, c = lane & 15;

    // B fragments (identical for all waves; L1/L2-broadcast)
    bf8_t Bh[KT][2], Bl[KT][2];
#pragma unroll
    for (int kt = 0; kt < KT; ++kt)
#pragma unroll
        for (int nt = 0; nt < 2; ++nt) {
            Bh[kt][nt] = *(const bf8_t*)(wh + ((size_t)(kt * 2 + nt) * 64 + lane) * 8);
            Bl[kt][nt] = *(const bf8_t*)(wl + ((size_t)(kt * 2 + nt) * 64 + lane) * 8);
        }

    // A fragments: row = m0 + c, k = kt*32 + q*8 + j  (coalesced 32 B/lane)
    int rowa = m0 + c;
    if (rowa >= N) rowa = N - 1;
    const float* xr = x + (size_t)rowa * FIN;
    bf8_t Ah[KT], Al[KT];
#pragma unroll
    for (int kt = 0; kt < KT; ++kt) {
        f32x4 v0 = *(const f32x4*)(xr + kt * 32 + q * 8);
        f32x4 v1 = *(const f32x4*)(xr + kt * 32 + q * 8 + 4);
#pragma unroll
        for (int j = 0; j < 8; ++j) {
            float f = (j < 4) ? v0[j] : v1[j - 4];
            unsigned short hi = f2bf(f);
            Ah[kt][j] = (short)hi;
            Al[kt][j] = (short)f2bf(f - bf2f(hi));
        }
    }

    f32x4 acc0 = {0.f, 0.f, 0.f, 0.f}, acc1 = {0.f, 0.f, 0.f, 0.f};
#pragma unroll
    for (int kt = 0; kt < KT; ++kt) {
        acc0 = __builtin_amdgcn_mfma_f32_16x16x32_bf16(Ah[kt], Bh[kt][0], acc0, 0, 0, 0);
        acc1 = __builtin_amdgcn_mfma_f32_16x16x32_bf16(Ah[kt], Bh[kt][1], acc1, 0, 0, 0);
        acc0 = __builtin_amdgcn_mfma_f32_16x16x32_bf16(Al[kt], Bh[kt][0], acc0, 0, 0, 0);
        acc1 = __builtin_amdgcn_mfma_f32_16x16x32_bf16(Al[kt], Bh[kt][1], acc1, 0, 0, 0);
        acc0 = __builtin_amdgcn_mfma_f32_16x16x32_bf16(Ah[kt], Bl[kt][0], acc0, 0, 0, 0);
        acc1 = __builtin_amdgcn_mfma_f32_16x16x32_bf16(Ah[kt], Bl[kt][1], acc1, 0, 0, 0);
    }

    // D layout: col = lane&15, row = q*4 + reg
#pragma unroll
    for (int reg = 0; reg < 4; ++reg) {
        int r = m0 + q * 4 + reg;
        if (r < N) {
            float v0s = acc0[reg], v1s = acc1[reg];
            if (!ATT) { v0s += bias[c]; v1s += bias[c + 16]; }
            h[(size_t)r * 32 + c]      = v0s;
            h[(size_t)r * 32 + 16 + c] = v1s;
        }
    }
    if (ATT) {
        float as0 = a_s[c], as1 = a_s[c + 16];
        float ad0 = a_d[c], ad1 = a_d[c + 16];
#pragma unroll
        for (int reg = 0; reg < 4; ++reg) {
            float ps = acc0[reg] * as0 + acc1[reg] * as1;
            float pd = acc0[reg] * ad0 + acc1[reg] * ad1;
#pragma unroll
            for (int msk = 8; msk >= 1; msk >>= 1) {
                ps += __shfl_xor(ps, msk);
                pd += __shfl_xor(pd, msk);
            }
            int r = m0 + q * 4 + reg;
            if (c == 0 && r < N) {
                alpha_s[r] = ps;
                alpha_d[r] = pd;
            }
        }
    }
}

// ---------------- aggregation ----------------
// 8 lanes per node, float4 features per lane. Per-edge weight computed ONCE by
// the chunk-owning lane, broadcast via width-8 shuffle. 32-edge chunks: 4 csr
// loads + 4 alpha gathers + 4 exps batched per lane -> dependent chain
// (csr -> alpha -> exp -> shfl -> h-gather) restarts 4x less often; 32
// independent h-row gathers in flight per chunk (was 8; latency-bound at
// VALUBusy 16%, HBM 41%).
__global__ __launch_bounds__(256) void fused_agg(
    const int* __restrict__ csr, const int* __restrict__ off,
    const float* __restrict__ alpha_s, const float* __restrict__ alpha_d,
    const float* __restrict__ h, const float* __restrict__ bias,
    float* __restrict__ out, int N)
{
    int t = blockIdx.x * 256 + threadIdx.x;
    int i = t >> 3, q = t & 7;          // node i, feature quad q (k = q*4..q*4+3)
    if (i >= N) return;
    int s0 = off[i], s1 = off[i + 1];
    float ad = alpha_d[i];

    const float* hq = h + q * 4;        // per-lane feature base

    // self loop
    float w   = __expf(leaky(alpha_s[i] + ad));
    float den = w;
    f32x4 hv  = *(const f32x4*)(hq + (size_t)i * 32);
    f32x4 acc;
    acc[0] = w * hv[0]; acc[1] = w * hv[1]; acc[2] = w * hv[2]; acc[3] = w * hv[3];

    int j = s0;
    // 32-edge chunks: lane q owns edges j+q, j+8+q, j+16+q, j+24+q (coalesced)
    for (; j + 32 <= s1; j += 32) {
        int c0 = csr[j + q];
        int c1 = csr[j + 8 + q];
        int c2 = csr[j + 16 + q];
        int c3 = csr[j + 24 + q];
        float a0 = alpha_s[c0], a1 = alpha_s[c1], a2 = alpha_s[c2], a3 = alpha_s[c3];
        float w0 = __expf(leaky(a0 + ad));
        float w1 = __expf(leaky(a1 + ad));
        float w2 = __expf(leaky(a2 + ad));
        float w3 = __expf(leaky(a3 + ad));
        int o0 = c0 << 5, o1 = c1 << 5, o2 = c2 << 5, o3 = c3 << 5;
#pragma unroll
        for (int e = 0; e < 8; ++e) {
            int   e0 = __shfl(o0, e, 8); float f0 = __shfl(w0, e, 8);
            int   e1 = __shfl(o1, e, 8); float f1 = __shfl(w1, e, 8);
            int   e2 = __shfl(o2, e, 8); float f2 = __shfl(w2, e, 8);
            int   e3 = __shfl(o3, e, 8); float f3 = __shfl(w3, e, 8);
            f32x4 g0 = *(const f32x4*)(hq + e0);
            f32x4 g1 = *(const f32x4*)(hq + e1);
            f32x4 g2 = *(const f32x4*)(hq + e2);
            f32x4 g3 = *(const f32x4*)(hq + e3);
            den += (f0 + f1) + (f2 + f3);
            acc[0] += f0 * g0[0]; acc[1] += f0 * g0[1];
            acc[2] += f0 * g0[2]; acc[3] += f0 * g0[3];
            acc[0] += f1 * g1[0]; acc[1] += f1 * g1[1];
            acc[2] += f1 * g1[2]; acc[3] += f1 * g1[3];
            acc[0] += f2 * g2[0]; acc[1] += f2 * g2[1];
            acc[2] += f2 * g2[2]; acc[3] += f2 * g2[3];
            acc[0] += f3 * g3[0]; acc[1] += f3 * g3[1];
            acc[2] += f3 * g3[2]; acc[3] += f3 * g3[3];
        }
    }
    // 8-edge chunks
    for (; j + 8 <= s1; j += 8) {
        int   c  = csr[j + q];
        float wv = __expf(leaky(alpha_s[c] + ad));
        int   co = c << 5;
#pragma unroll
        for (int e = 0; e < 8; ++e) {
            int   ce = __shfl(co, e, 8);
            float we = __shfl(wv, e, 8);
            f32x4 hg = *(const f32x4*)(hq + ce);
            den += we;
            acc[0] += we * hg[0]; acc[1] += we * hg[1];
            acc[2] += we * hg[2]; acc[3] += we * hg[3];
        }
    }
    // tail (< 8 edges)
    int rem = s1 - j;
    if (rem > 0) {
        int c = 0; float wv = 0.0f;
        if (q < rem) {
            c  = csr[j + q];
            wv = __expf(leaky(alpha_s[c] + ad));
        }
        int co = c << 5;
        for (int e = 0; e < rem; ++e) {
            int   ce = __shfl(co, e, 8);
            float we = __shfl(wv, e, 8);
            f32x4 hg = *(const f32x4*)(hq + ce);
            den += we;
            acc[0] += we * hg[0]; acc[1] += we * hg[1];
            acc[2] += we * hg[2]; acc[3] += we * hg[3];
        }
    }

    float inv = 1.0f / den;
    f32x4 b4  = *(const f32x4*)(bias + q * 4);
    f32x4 r;
    r[0] = fmaxf(acc[0] * inv + b4[0], 0.0f);
    r[1] = fmaxf(acc[1] * inv + b4[1], 0.0f);
    r[2] = fmaxf(acc[2] * inv + b4[2], 0.0f);
    r[3] = fmaxf(acc[3] * inv + b4[3], 0.0f);
    *(f32x4*)(out + (size_t)i * 32 + q * 4) = r;
}

extern "C" void kernel_launch(void* const* d_in, const int* in_sizes, int n_in,
                              void* d_out, int out_size, void* d_ws, size_t ws_size,
                              hipStream_t stream)
{
    const float* x   = (const float*)d_in[0];
    const int*   ei  = (const int*)d_in[1];
    const float* W1  = (const float*)d_in[2];
    const float* a1s = (const float*)d_in[3];
    const float* a1d = (const float*)d_in[4];
    const float* b1  = (const float*)d_in[5];
    const float* W2  = (const float*)d_in[6];
    const float* a2s = (const float*)d_in[7];
    const float* a2d = (const float*)d_in[8];
    const float* b2  = (const float*)d_in[9];
    const float* Wf  = (const float*)d_in[10];
    const float* bf  = (const float*)d_in[11];

    const int N = in_sizes[0] / 128;
    const int E = in_sizes[1] / 2;
    const int* esrc = ei;
    const int* edst = ei + E;
    const int B1 = (N + BK_NODES - 1) >> BK_LOG;

    // Workspace (4B units): h1 32N | h2 32N | alpha_s N | alpha_d N |
    //   off N+1 | csr E | bcnt 256 | bbase 257 | bcur 256 | wfrag arrays
    float* ws = (float*)d_ws;
    float* h1      = ws;
    float* h2      = h1 + (size_t)N * 32;
    float* alpha_s = h2 + (size_t)N * 32;
    float* alpha_d = alpha_s + N;
    int*   off     = (int*)(alpha_d + N);
    int*   csr     = off + (N + 1);
    int*   bcnt    = csr + E;
    int*   bbase   = bcnt + 256;
    int*   bcur    = bbase + 257;
    unsigned short* wfb =
        (unsigned short*)(((uintptr_t)(bcur + 256) + 15) & ~(uintptr_t)15);
    unsigned short* wh1 = wfb;            // 4096 each for K=128
    unsigned short* wl1 = wh1 + 4096;
    unsigned short* wh2 = wl1 + 4096;     // 1024 each for K=32
    unsigned short* wl2 = wh2 + 1024;
    unsigned short* whf = wl2 + 1024;
    unsigned short* wlf = whf + 1024;
    // pairs (E uint32, packed) aliases h1 (build completes before h is live)
    unsigned* pairs = ((size_t)E <= (size_t)64 * N)
                          ? (unsigned*)h1
                          : (unsigned*)(wlf + 1024);

    const int nb_agg  = (N * 8 + 255) / 256;
    const int nb_tile = (E + TILE_E - 1) / TILE_E;
    const int nb_gemm = ((N + 15) / 16 + 3) / 4;

    // ---- weight fragment precompute ----
    k_wsplit<<<2, 256, 0, stream>>>(W1, wh1, wl1, 128);
    k_wsplit<<<1, 256, 0, stream>>>(W2, wh2, wl2, 32);
    k_wsplit<<<1, 256, 0, stream>>>(Wf, whf, wlf, 32);

    // ---- CSR build ----
    k_bzero  <<<1, 256, 0, stream>>>(bcnt);
    k_bcount <<<nb_tile, 256, 0, stream>>>(edst, bcnt, E);
    k_bscan  <<<1, 256, 0, stream>>>(bcnt, bbase, bcur, off, N, E);
    k_bplace <<<nb_tile, 256, 0, stream>>>(esrc, edst, bcur, pairs, E);
    k_csr    <<<B1, 512, 0, stream>>>(bbase, pairs, off, csr, N);

    // ---- layer 1 ----
    gemm_mfma<128, true><<<nb_gemm, 256, 0, stream>>>(
        x, wh1, wl1, a1s, a1d, nullptr, h1, alpha_s, alpha_d, N);
    fused_agg<<<nb_agg, 256, 0, stream>>>(csr, off, alpha_s, alpha_d, h1, b1, h2, N);

    // ---- layer 2 ----
    gemm_mfma<32, true><<<nb_gemm, 256, 0, stream>>>(
        h2, wh2, wl2, a2s, a2d, nullptr, h1, alpha_s, alpha_d, N);
    fused_agg<<<nb_agg, 256, 0, stream>>>(csr, off, alpha_s, alpha_d, h1, b2, h2, N);

    // ---- final linear ----
    gemm_mfma<32, false><<<nb_gemm, 256, 0, stream>>>(
        h2, whf, wlf, nullptr, nullptr, bf, (float*)d_out, nullptr, nullptr, N);
}

// Round 4
// 339.048 us; speedup vs baseline: 1.1603x; 1.0421x over previous
//
#include <hip/hip_runtime.h>

#define NEG_SLOPE 0.2f
#define BK_LOG 9
#define BK_NODES (1 << BK_LOG)       // 512 nodes per bucket
#define TILE_EPT 24
#define TILE_E (256 * TILE_EPT)      // 6144 edges per partition tile

typedef __attribute__((ext_vector_type(8))) short bf8_t;   // 8 bf16 (4 VGPRs)
typedef __attribute__((ext_vector_type(4))) float f32x4;

__device__ __forceinline__ float leaky(float v) { return v > 0.0f ? v : NEG_SLOPE * v; }

// fp32 -> bf16 (RNE) bit tricks; inputs are finite (no NaN handling needed)
__device__ __forceinline__ unsigned short f2bf(float f) {
    unsigned u = __float_as_uint(f);
    u += 0x7fffu + ((u >> 16) & 1u);
    return (unsigned short)(u >> 16);
}
__device__ __forceinline__ float bf2f(unsigned short h) {
    return __uint_as_float(((unsigned)h) << 16);
}

// exclusive scan of one value per thread across a 256-thread block
__device__ __forceinline__ int scan256_excl(int v, int* tmp) {
    int t = threadIdx.x;
    tmp[t] = v;
    __syncthreads();
    for (int d = 1; d < 256; d <<= 1) {
        int x = (t >= d) ? tmp[t - d] : 0;
        __syncthreads();
        tmp[t] += x;
        __syncthreads();
    }
    int r = tmp[t] - v;
    __syncthreads();
    return r;
}

// ---------------- weight split bodies (merged into k_prep) ----------------
// W [K][32] -> pre-swizzled B fragments in MFMA lane order:
//   wf[((kt*2+nt)*64 + lane)*8 + j] holds W[kt*32 + (lane>>4)*8 + j][nt*16 + (lane&15)]
__device__ __forceinline__ void wsplit_body(int blk, int tid,
                                            const float* __restrict__ W,
                                            unsigned short* __restrict__ wh,
                                            unsigned short* __restrict__ wl, int K) {
    int idx = blk * 256 + tid;
    int KT = K >> 5;
    if (idx >= KT * 128) return;       // KT*2*64 fragments-of-8
    int lane = idx & 63;
    int nt = (idx >> 6) & 1;
    int kt = idx >> 7;
    int q = lane >> 4, c = lane & 15;
#pragma unroll
    for (int j = 0; j < 8; ++j) {
        int k = kt * 32 + q * 8 + j;
        int n = nt * 16 + c;
        float w = W[k * 32 + n];
        unsigned short hi = f2bf(w);
        wh[idx * 8 + j] = hi;
        wl[idx * 8 + j] = f2bf(w - bf2f(hi));
    }
}

// blocks 0-1: W1 split; block 2: W2; block 3: Wf; block 4: zero bcnt
__global__ __launch_bounds__(256) void k_prep(
    const float* __restrict__ W1, unsigned short* __restrict__ wh1, unsigned short* __restrict__ wl1,
    const float* __restrict__ W2, unsigned short* __restrict__ wh2, unsigned short* __restrict__ wl2,
    const float* __restrict__ Wf, unsigned short* __restrict__ whf, unsigned short* __restrict__ wlf,
    int* __restrict__ bcnt)
{
    int b = blockIdx.x, t = threadIdx.x;
    if (b < 2)       wsplit_body(b, t, W1, wh1, wl1, 128);
    else if (b == 2) wsplit_body(0, t, W2, wh2, wl2, 32);
    else if (b == 3) wsplit_body(0, t, Wf, whf, wlf, 32);
    else             bcnt[t] = 0;
}

// ---------------- MFMA GEMM body (split-bf16, fp32-class accuracy) ----------
// One wave per 16-row M-tile. x split to (hi,lo) bf16 in-flight; 3 MFMA passes.
// ATT: also alpha_s/alpha_d via cross-lane reduce.  !ATT: adds bias (final gemm).
template <int FIN, bool ATT>
__device__ __forceinline__ void gemm_body(
    int blk, int tid,
    const float* __restrict__ x,
    const unsigned short* __restrict__ wh, const unsigned short* __restrict__ wl,
    const float* __restrict__ a_s, const float* __restrict__ a_d,
    const float* __restrict__ bias,
    float* __restrict__ h, float* __restrict__ alpha_s,
    float* __restrict__ alpha_d, int N)
{
    constexpr int KT = FIN / 32;
    int lane = tid & 63;
    int mt   = blk * 4 + (tid >> 6);
    int m0   = mt * 16;
    if (m0 >= N) return;
    int q = lane >> 4, c = lane & 15;

    // B fragments (identical for all waves; L1/L2-broadcast)
    bf8_t Bh[KT][2], Bl[KT][2];
#pragma unroll
    for (int kt = 0; kt < KT; ++kt)
#pragma unroll
        for (int nt = 0; nt < 2; ++nt) {
            Bh[kt][nt] = *(const bf8_t*)(wh + ((size_t)(kt * 2 + nt) * 64 + lane) * 8);
            Bl[kt][nt] = *(const bf8_t*)(wl + ((size_t)(kt * 2 + nt) * 64 + lane) * 8);
        }

    // A fragments: row = m0 + c, k = kt*32 + q*8 + j  (coalesced 32 B/lane)
    int rowa = m0 + c;
    if (rowa >= N) rowa = N - 1;
    const float* xr = x + (size_t)rowa * FIN;
    bf8_t Ah[KT], Al[KT];
#pragma unroll
    for (int kt = 0; kt < KT; ++kt) {
        f32x4 v0 = *(const f32x4*)(xr + kt * 32 + q * 8);
        f32x4 v1 = *(const f32x4*)(xr + kt * 32 + q * 8 + 4);
#pragma unroll
        for (int j = 0; j < 8; ++j) {
            float f = (j < 4) ? v0[j] : v1[j - 4];
            unsigned short hi = f2bf(f);
            Ah[kt][j] = (short)hi;
            Al[kt][j] = (short)f2bf(f - bf2f(hi));
        }
    }

    f32x4 acc0 = {0.f, 0.f, 0.f, 0.f}, acc1 = {0.f, 0.f, 0.f, 0.f};
#pragma unroll
    for (int kt = 0; kt < KT; ++kt) {
        acc0 = __builtin_amdgcn_mfma_f32_16x16x32_bf16(Ah[kt], Bh[kt][0], acc0, 0, 0, 0);
        acc1 = __builtin_amdgcn_mfma_f32_16x16x32_bf16(Ah[kt], Bh[kt][1], acc1, 0, 0, 0);
        acc0 = __builtin_amdgcn_mfma_f32_16x16x32_bf16(Al[kt], Bh[kt][0], acc0, 0, 0, 0);
        acc1 = __builtin_amdgcn_mfma_f32_16x16x32_bf16(Al[kt], Bh[kt][1], acc1, 0, 0, 0);
        acc0 = __builtin_amdgcn_mfma_f32_16x16x32_bf16(Ah[kt], Bl[kt][0], acc0, 0, 0, 0);
        acc1 = __builtin_amdgcn_mfma_f32_16x16x32_bf16(Ah[kt], Bl[kt][1], acc1, 0, 0, 0);
    }

    // D layout: col = lane&15, row = q*4 + reg
#pragma unroll
    for (int reg = 0; reg < 4; ++reg) {
        int r = m0 + q * 4 + reg;
        if (r < N) {
            float v0s = acc0[reg], v1s = acc1[reg];
            if (!ATT) { v0s += bias[c]; v1s += bias[c + 16]; }
            h[(size_t)r * 32 + c]      = v0s;
            h[(size_t)r * 32 + 16 + c] = v1s;
        }
    }
    if (ATT) {
        float as0 = a_s[c], as1 = a_s[c + 16];
        float ad0 = a_d[c], ad1 = a_d[c + 16];
#pragma unroll
        for (int reg = 0; reg < 4; ++reg) {
            float ps = acc0[reg] * as0 + acc1[reg] * as1;
            float pd = acc0[reg] * ad0 + acc1[reg] * ad1;
#pragma unroll
            for (int msk = 8; msk >= 1; msk >>= 1) {
                ps += __shfl_xor(ps, msk);
                pd += __shfl_xor(pd, msk);
            }
            int r = m0 + q * 4 + reg;
            if (c == 0 && r < N) {
                alpha_s[r] = ps;
                alpha_d[r] = pd;
            }
        }
    }
}

template <int FIN, bool ATT>
__global__ __launch_bounds__(256) void gemm_mfma(
    const float* __restrict__ x,
    const unsigned short* __restrict__ wh, const unsigned short* __restrict__ wl,
    const float* __restrict__ a_s, const float* __restrict__ a_d,
    const float* __restrict__ bias,
    float* __restrict__ h, float* __restrict__ alpha_s,
    float* __restrict__ alpha_d, int N)
{
    gemm_body<FIN, ATT>(blockIdx.x, threadIdx.x, x, wh, wl, a_s, a_d, bias,
                        h, alpha_s, alpha_d, N);
}

// ---------------- bcount + gemm1 combined (independent work, one dispatch) --
__global__ __launch_bounds__(256) void k_bcount_gemm1(
    const int* __restrict__ edst, int* __restrict__ bcnt, int E, int nb_tile,
    const float* __restrict__ x,
    const unsigned short* __restrict__ wh, const unsigned short* __restrict__ wl,
    const float* __restrict__ a_s, const float* __restrict__ a_d,
    float* __restrict__ h, float* __restrict__ alpha_s,
    float* __restrict__ alpha_d, int N)
{
    if ((int)blockIdx.x < nb_tile) {
        __shared__ int th[256];
        int t = threadIdx.x;
        th[t] = 0;
        __syncthreads();
        int base = blockIdx.x * TILE_E;
#pragma unroll
        for (int k = 0; k < TILE_EPT; ++k) {
            int e = base + t + k * 256;
            if (e < E) atomicAdd(&th[edst[e] >> BK_LOG], 1);
        }
        __syncthreads();
        if (th[t]) atomicAdd(&bcnt[t], th[t]);
    } else {
        gemm_body<128, true>(blockIdx.x - nb_tile, threadIdx.x, x, wh, wl,
                             a_s, a_d, nullptr, h, alpha_s, alpha_d, N);
    }
}

// ---------------- edge partition (counting sort by dst-bucket) ----------------

__global__ __launch_bounds__(256) void k_bscan(const int* __restrict__ bcnt,
                                               int* __restrict__ bbase,
                                               int* __restrict__ bcur,
                                               int* __restrict__ off, int N, int E) {
    __shared__ int tmp[256];
    int t = threadIdx.x;
    int ex = scan256_excl(bcnt[t], tmp);
    bbase[t] = ex;
    bcur[t]  = ex;
    if (t == 0) { bbase[256] = E; off[N] = E; }
}

// pairs packed: (src << BK_LOG) | (dst & (BK_NODES-1)); bucket implied by position
__global__ __launch_bounds__(256) void k_bplace(const int* __restrict__ esrc,
                                                const int* __restrict__ edst,
                                                int* __restrict__ bcur,
                                                unsigned* __restrict__ pairs, int E) {
    __shared__ int2 sp[TILE_E];
    __shared__ int th[256], tx[256], rb[256], tmp[256];
    int t = threadIdx.x;
    th[t] = 0;
    __syncthreads();
    int base = blockIdx.x * TILE_E;
    int tot  = min(TILE_E, E - base);
#pragma unroll
    for (int k = 0; k < TILE_EPT; ++k) {
        int e = base + t + k * 256;
        if (e < E) atomicAdd(&th[edst[e] >> BK_LOG], 1);
    }
    __syncthreads();
    int cnt = th[t];
    tx[t] = scan256_excl(cnt, tmp);
    rb[t] = atomicAdd(&bcur[t], cnt);
    th[t] = 0;
    __syncthreads();
#pragma unroll
    for (int k = 0; k < TILE_EPT; ++k) {
        int e = base + t + k * 256;
        if (e < E) {
            int s = esrc[e], d = edst[e];
            int b = d >> BK_LOG;
            int r = atomicAdd(&th[b], 1);
            sp[tx[b] + r] = make_int2(s, d);
        }
    }
    __syncthreads();
    for (int i = t; i < tot; i += 256) {
        int2 p = sp[i];
        int  b = p.y >> BK_LOG;
        pairs[rb[b] + (i - tx[b])] =
            ((unsigned)p.x << BK_LOG) | (unsigned)(p.y & (BK_NODES - 1));
    }
}

// 512 threads: one bucket (512 nodes) per block, 1 node per thread
__global__ __launch_bounds__(512) void k_csr(const int* __restrict__ bbase,
                                             const unsigned* __restrict__ pairs,
                                             int* __restrict__ off,
                                             int* __restrict__ csr, int N) {
    __shared__ int lh[BK_NODES], lx[BK_NODES];
    int b = blockIdx.x, t = threadIdx.x;
    int lo = bbase[b], hi = bbase[b + 1];
    int node0 = b << BK_LOG;
    lh[t] = 0;
    __syncthreads();
    for (int j = lo + t; j < hi; j += 512)
        atomicAdd(&lh[pairs[j] & (BK_NODES - 1)], 1);
    __syncthreads();
    lx[t] = lh[t];
    __syncthreads();
    for (int d = 1; d < BK_NODES; d <<= 1) {
        int x0 = (t >= d) ? lx[t - d] : 0;
        __syncthreads();
        lx[t] += x0;
        __syncthreads();
    }
    lx[t] -= lh[t];
    if (node0 + t < N) off[node0 + t] = lo + lx[t];
    lh[t] = 0;
    __syncthreads();
    for (int j = lo + t; j < hi; j += 512) {
        unsigned p  = pairs[j];
        int      li = p & (BK_NODES - 1);
        int      r  = atomicAdd(&lh[li], 1);
        csr[lo + lx[li] + r] = (int)(p >> BK_LOG);
    }
}

// ---------------- aggregation ----------------
// 8 lanes per node, float4 features per lane. Per-edge weight computed ONCE by
// the chunk-owning lane, broadcast via width-8 shuffle. Single masked 32-wide
// loop: invalid edge slots get w=0, c=0 (zero-weight FMA against cached row 0
// is an exact no-op) -> removes the 8-chunk + tail divergence phases; wave
// iterations = max(ceil(deg/32)) flat.
__global__ __launch_bounds__(256) void fused_agg(
    const int* __restrict__ csr, const int* __restrict__ off,
    const float* __restrict__ alpha_s, const float* __restrict__ alpha_d,
    const float* __restrict__ h, const float* __restrict__ bias,
    float* __restrict__ out, int N)
{
    int t = blockIdx.x * 256 + threadIdx.x;
    int i = t >> 3, q = t & 7;          // node i, feature quad q (k = q*4..q*4+3)
    if (i >= N) return;
    int s0 = off[i], s1 = off[i + 1];
    float ad = alpha_d[i];

    const float* hq = h + q * 4;        // per-lane feature base

    // self loop
    float w   = __expf(leaky(alpha_s[i] + ad));
    float den = w;
    f32x4 hv  = *(const f32x4*)(hq + (size_t)i * 32);
    f32x4 acc;
    acc[0] = w * hv[0]; acc[1] = w * hv[1]; acc[2] = w * hv[2]; acc[3] = w * hv[3];

    for (int j = s0; j < s1; j += 32) {
        int i0 = j + q, i1 = i0 + 8, i2 = i0 + 16, i3 = i0 + 24;
        int c0 = (i0 < s1) ? csr[i0] : 0;
        int c1 = (i1 < s1) ? csr[i1] : 0;
        int c2 = (i2 < s1) ? csr[i2] : 0;
        int c3 = (i3 < s1) ? csr[i3] : 0;
        float e0x = __expf(leaky(alpha_s[c0] + ad));
        float e1x = __expf(leaky(alpha_s[c1] + ad));
        float e2x = __expf(leaky(alpha_s[c2] + ad));
        float e3x = __expf(leaky(alpha_s[c3] + ad));
        float w0 = (i0 < s1) ? e0x : 0.0f;
        float w1 = (i1 < s1) ? e1x : 0.0f;
        float w2 = (i2 < s1) ? e2x : 0.0f;
        float w3 = (i3 < s1) ? e3x : 0.0f;
        int o0 = c0 << 5, o1 = c1 << 5, o2 = c2 << 5, o3 = c3 << 5;
#pragma unroll
        for (int e = 0; e < 8; ++e) {
            int   e0 = __shfl(o0, e, 8); float f0 = __shfl(w0, e, 8);
            int   e1 = __shfl(o1, e, 8); float f1 = __shfl(w1, e, 8);
            int   e2 = __shfl(o2, e, 8); float f2 = __shfl(w2, e, 8);
            int   e3 = __shfl(o3, e, 8); float f3 = __shfl(w3, e, 8);
            f32x4 g0 = *(const f32x4*)(hq + e0);
            f32x4 g1 = *(const f32x4*)(hq + e1);
            f32x4 g2 = *(const f32x4*)(hq + e2);
            f32x4 g3 = *(const f32x4*)(hq + e3);
            den += (f0 + f1) + (f2 + f3);
            acc[0] += f0 * g0[0]; acc[1] += f0 * g0[1];
            acc[2] += f0 * g0[2]; acc[3] += f0 * g0[3];
            acc[0] += f1 * g1[0]; acc[1] += f1 * g1[1];
            acc[2] += f1 * g1[2]; acc[3] += f1 * g1[3];
            acc[0] += f2 * g2[0]; acc[1] += f2 * g2[1];
            acc[2] += f2 * g2[2]; acc[3] += f2 * g2[3];
            acc[0] += f3 * g3[0]; acc[1] += f3 * g3[1];
            acc[2] += f3 * g3[2]; acc[3] += f3 * g3[3];
        }
    }

    float inv = 1.0f / den;
    f32x4 b4  = *(const f32x4*)(bias + q * 4);
    f32x4 r;
    r[0] = fmaxf(acc[0] * inv + b4[0], 0.0f);
    r[1] = fmaxf(acc[1] * inv + b4[1], 0.0f);
    r[2] = fmaxf(acc[2] * inv + b4[2], 0.0f);
    r[3] = fmaxf(acc[3] * inv + b4[3], 0.0f);
    *(f32x4*)(out + (size_t)i * 32 + q * 4) = r;
}

extern "C" void kernel_launch(void* const* d_in, const int* in_sizes, int n_in,
                              void* d_out, int out_size, void* d_ws, size_t ws_size,
                              hipStream_t stream)
{
    const float* x   = (const float*)d_in[0];
    const int*   ei  = (const int*)d_in[1];
    const float* W1  = (const float*)d_in[2];
    const float* a1s = (const float*)d_in[3];
    const float* a1d = (const float*)d_in[4];
    const float* b1  = (const float*)d_in[5];
    const float* W2  = (const float*)d_in[6];
    const float* a2s = (const float*)d_in[7];
    const float* a2d = (const float*)d_in[8];
    const float* b2  = (const float*)d_in[9];
    const float* Wf  = (const float*)d_in[10];
    const float* bf  = (const float*)d_in[11];

    const int N = in_sizes[0] / 128;
    const int E = in_sizes[1] / 2;
    const int* esrc = ei;
    const int* edst = ei + E;
    const int B1 = (N + BK_NODES - 1) >> BK_LOG;

    // Workspace (4B units): h1 32N | h2 32N | alpha_s N | alpha_d N |
    //   off N+1 | csr E | bcnt 256 | bbase 257 | bcur 256 | wfrag arrays
    float* ws = (float*)d_ws;
    float* h1      = ws;
    float* h2      = h1 + (size_t)N * 32;
    float* alpha_s = h2 + (size_t)N * 32;
    float* alpha_d = alpha_s + N;
    int*   off     = (int*)(alpha_d + N);
    int*   csr     = off + (N + 1);
    int*   bcnt    = csr + E;
    int*   bbase   = bcnt + 256;
    int*   bcur    = bbase + 257;
    unsigned short* wfb =
        (unsigned short*)(((uintptr_t)(bcur + 256) + 15) & ~(uintptr_t)15);
    unsigned short* wh1 = wfb;            // 4096 each for K=128
    unsigned short* wl1 = wh1 + 4096;
    unsigned short* wh2 = wl1 + 4096;     // 1024 each for K=32
    unsigned short* wl2 = wh2 + 1024;
    unsigned short* whf = wl2 + 1024;
    unsigned short* wlf = whf + 1024;
    // pairs (E uint32, packed) aliases h2: gemm1 now runs BEFORE bplace (it
    // writes h1), so the alias target must be h2, which stays dead until agg1.
    unsigned* pairs = ((size_t)E <= (size_t)32 * N)
                          ? (unsigned*)h2
                          : (unsigned*)(wlf + 1024);

    const int nb_agg  = (N * 8 + 255) / 256;
    const int nb_tile = (E + TILE_E - 1) / TILE_E;
    const int nb_gemm = ((N + 15) / 16 + 3) / 4;

    // ---- prep: weight fragments + bcnt zero (1 dispatch) ----
    k_prep<<<5, 256, 0, stream>>>(W1, wh1, wl1, W2, wh2, wl2, Wf, whf, wlf, bcnt);

    // ---- bucket count + layer-1 GEMM (independent; 1 dispatch) ----
    k_bcount_gemm1<<<nb_tile + nb_gemm, 256, 0, stream>>>(
        edst, bcnt, E, nb_tile, x, wh1, wl1, a1s, a1d, h1, alpha_s, alpha_d, N);

    // ---- CSR build ----
    k_bscan  <<<1, 256, 0, stream>>>(bcnt, bbase, bcur, off, N, E);
    k_bplace <<<nb_tile, 256, 0, stream>>>(esrc, edst, bcur, pairs, E);
    k_csr    <<<B1, 512, 0, stream>>>(bbase, pairs, off, csr, N);

    // ---- layer 1 aggregate ----
    fused_agg<<<nb_agg, 256, 0, stream>>>(csr, off, alpha_s, alpha_d, h1, b1, h2, N);

    // ---- layer 2 ----
    gemm_mfma<32, true><<<nb_gemm, 256, 0, stream>>>(
        h2, wh2, wl2, a2s, a2d, nullptr, h1, alpha_s, alpha_d, N);
    fused_agg<<<nb_agg, 256, 0, stream>>>(csr, off, alpha_s, alpha_d, h1, b2, h2, N);

    // ---- final linear ----
    gemm_mfma<32, false><<<nb_gemm, 256, 0, stream>>>(
        h2, whf, wlf, nullptr, nullptr, bf, (float*)d_out, nullptr, nullptr, N);
}

// Round 5
// 338.397 us; speedup vs baseline: 1.1626x; 1.0019x over previous
//
#include <hip/hip_runtime.h>

#define NEG_SLOPE 0.2f
#define BK_LOG 9
#define BK_NODES (1 << BK_LOG)       // 512 nodes per bucket
#define TILE_EPT 24
#define TILE_E (256 * TILE_EPT)      // 6144 edges per partition tile

typedef __attribute__((ext_vector_type(8))) short bf8_t;   // 8 bf16 (4 VGPRs)
typedef __attribute__((ext_vector_type(4))) float f32x4;

__device__ __forceinline__ float leaky(float v) { return v > 0.0f ? v : NEG_SLOPE * v; }

// fp32 -> bf16 (RNE) bit tricks; inputs are finite (no NaN handling needed)
__device__ __forceinline__ unsigned short f2bf(float f) {
    unsigned u = __float_as_uint(f);
    u += 0x7fffu + ((u >> 16) & 1u);
    return (unsigned short)(u >> 16);
}
__device__ __forceinline__ float bf2f(unsigned short h) {
    return __uint_as_float(((unsigned)h) << 16);
}

// exclusive scan of one value per thread across a 256-thread block
__device__ __forceinline__ int scan256_excl(int v, int* tmp) {
    int t = threadIdx.x;
    tmp[t] = v;
    __syncthreads();
    for (int d = 1; d < 256; d <<= 1) {
        int x = (t >= d) ? tmp[t - d] : 0;
        __syncthreads();
        tmp[t] += x;
        __syncthreads();
    }
    int r = tmp[t] - v;
    __syncthreads();
    return r;
}

// ---------------- weight split bodies (merged into k_prep) ----------------
// W [K][32] -> pre-swizzled B fragments in MFMA lane order:
//   wf[((kt*2+nt)*64 + lane)*8 + j] holds W[kt*32 + (lane>>4)*8 + j][nt*16 + (lane&15)]
__device__ __forceinline__ void wsplit_body(int blk, int tid,
                                            const float* __restrict__ W,
                                            unsigned short* __restrict__ wh,
                                            unsigned short* __restrict__ wl, int K) {
    int idx = blk * 256 + tid;
    int KT = K >> 5;
    if (idx >= KT * 128) return;       // KT*2*64 fragments-of-8
    int lane = idx & 63;
    int nt = (idx >> 6) & 1;
    int kt = idx >> 7;
    int q = lane >> 4, c = lane & 15;
#pragma unroll
    for (int j = 0; j < 8; ++j) {
        int k = kt * 32 + q * 8 + j;
        int n = nt * 16 + c;
        float w = W[k * 32 + n];
        unsigned short hi = f2bf(w);
        wh[idx * 8 + j] = hi;
        wl[idx * 8 + j] = f2bf(w - bf2f(hi));
    }
}

// blocks 0-1: W1 split; block 2: zero bcnt
__global__ __launch_bounds__(256) void k_prep(
    const float* __restrict__ W1, unsigned short* __restrict__ wh1, unsigned short* __restrict__ wl1,
    int* __restrict__ bcnt)
{
    int b = blockIdx.x, t = threadIdx.x;
    if (b < 2) wsplit_body(b, t, W1, wh1, wl1, 128);
    else       bcnt[t] = 0;
}

// ---------------- MFMA GEMM body (split-bf16, fp32-class accuracy) ----------
// One wave per 16-row M-tile. x split to (hi,lo) bf16 in-flight; 3 MFMA passes.
// Computes h = x@W plus alpha_s/alpha_d via cross-lane reduce (layer-1 only).
template <int FIN>
__device__ __forceinline__ void gemm_body(
    int blk, int tid,
    const float* __restrict__ x,
    const unsigned short* __restrict__ wh, const unsigned short* __restrict__ wl,
    const float* __restrict__ a_s, const float* __restrict__ a_d,
    float* __restrict__ h, float* __restrict__ alpha_s,
    float* __restrict__ alpha_d, int N)
{
    constexpr int KT = FIN / 32;
    int lane = tid & 63;
    int mt   = blk * 4 + (tid >> 6);
    int m0   = mt * 16;
    if (m0 >= N) return;
    int q = lane >> 4, c = lane & 15;

    // B fragments (identical for all waves; L1/L2-broadcast)
    bf8_t Bh[KT][2], Bl[KT][2];
#pragma unroll
    for (int kt = 0; kt < KT; ++kt)
#pragma unroll
        for (int nt = 0; nt < 2; ++nt) {
            Bh[kt][nt] = *(const bf8_t*)(wh + ((size_t)(kt * 2 + nt) * 64 + lane) * 8);
            Bl[kt][nt] = *(const bf8_t*)(wl + ((size_t)(kt * 2 + nt) * 64 + lane) * 8);
        }

    // A fragments: row = m0 + c, k = kt*32 + q*8 + j  (coalesced 32 B/lane)
    int rowa = m0 + c;
    if (rowa >= N) rowa = N - 1;
    const float* xr = x + (size_t)rowa * FIN;
    bf8_t Ah[KT], Al[KT];
#pragma unroll
    for (int kt = 0; kt < KT; ++kt) {
        f32x4 v0 = *(const f32x4*)(xr + kt * 32 + q * 8);
        f32x4 v1 = *(const f32x4*)(xr + kt * 32 + q * 8 + 4);
#pragma unroll
        for (int j = 0; j < 8; ++j) {
            float f = (j < 4) ? v0[j] : v1[j - 4];
            unsigned short hi = f2bf(f);
            Ah[kt][j] = (short)hi;
            Al[kt][j] = (short)f2bf(f - bf2f(hi));
        }
    }

    f32x4 acc0 = {0.f, 0.f, 0.f, 0.f}, acc1 = {0.f, 0.f, 0.f, 0.f};
#pragma unroll
    for (int kt = 0; kt < KT; ++kt) {
        acc0 = __builtin_amdgcn_mfma_f32_16x16x32_bf16(Ah[kt], Bh[kt][0], acc0, 0, 0, 0);
        acc1 = __builtin_amdgcn_mfma_f32_16x16x32_bf16(Ah[kt], Bh[kt][1], acc1, 0, 0, 0);
        acc0 = __builtin_amdgcn_mfma_f32_16x16x32_bf16(Al[kt], Bh[kt][0], acc0, 0, 0, 0);
        acc1 = __builtin_amdgcn_mfma_f32_16x16x32_bf16(Al[kt], Bh[kt][1], acc1, 0, 0, 0);
        acc0 = __builtin_amdgcn_mfma_f32_16x16x32_bf16(Ah[kt], Bl[kt][0], acc0, 0, 0, 0);
        acc1 = __builtin_amdgcn_mfma_f32_16x16x32_bf16(Ah[kt], Bl[kt][1], acc1, 0, 0, 0);
    }

    // D layout: col = lane&15, row = q*4 + reg
#pragma unroll
    for (int reg = 0; reg < 4; ++reg) {
        int r = m0 + q * 4 + reg;
        if (r < N) {
            h[(size_t)r * 32 + c]      = acc0[reg];
            h[(size_t)r * 32 + 16 + c] = acc1[reg];
        }
    }
    float as0 = a_s[c], as1 = a_s[c + 16];
    float ad0 = a_d[c], ad1 = a_d[c + 16];
#pragma unroll
    for (int reg = 0; reg < 4; ++reg) {
        float ps = acc0[reg] * as0 + acc1[reg] * as1;
        float pd = acc0[reg] * ad0 + acc1[reg] * ad1;
#pragma unroll
        for (int msk = 8; msk >= 1; msk >>= 1) {
            ps += __shfl_xor(ps, msk);
            pd += __shfl_xor(pd, msk);
        }
        int r = m0 + q * 4 + reg;
        if (c == 0 && r < N) {
            alpha_s[r] = ps;
            alpha_d[r] = pd;
        }
    }
}

// ---------------- bcount + gemm1 combined (independent work, one dispatch) --
__global__ __launch_bounds__(256) void k_bcount_gemm1(
    const int* __restrict__ edst, int* __restrict__ bcnt, int E, int nb_tile,
    const float* __restrict__ x,
    const unsigned short* __restrict__ wh, const unsigned short* __restrict__ wl,
    const float* __restrict__ a_s, const float* __restrict__ a_d,
    float* __restrict__ h, float* __restrict__ alpha_s,
    float* __restrict__ alpha_d, int N)
{
    if ((int)blockIdx.x < nb_tile) {
        __shared__ int th[256];
        int t = threadIdx.x;
        th[t] = 0;
        __syncthreads();
        int base = blockIdx.x * TILE_E;
#pragma unroll
        for (int k = 0; k < TILE_EPT; ++k) {
            int e = base + t + k * 256;
            if (e < E) atomicAdd(&th[edst[e] >> BK_LOG], 1);
        }
        __syncthreads();
        if (th[t]) atomicAdd(&bcnt[t], th[t]);
    } else {
        gemm_body<128>(blockIdx.x - nb_tile, threadIdx.x, x, wh, wl,
                       a_s, a_d, h, alpha_s, alpha_d, N);
    }
}

// ---------------- edge partition (counting sort by dst-bucket) ----------------

__global__ __launch_bounds__(256) void k_bscan(const int* __restrict__ bcnt,
                                               int* __restrict__ bbase,
                                               int* __restrict__ bcur,
                                               int* __restrict__ off, int N, int E) {
    __shared__ int tmp[256];
    int t = threadIdx.x;
    int ex = scan256_excl(bcnt[t], tmp);
    bbase[t] = ex;
    bcur[t]  = ex;
    if (t == 0) { bbase[256] = E; off[N] = E; }
}

// pairs packed: (src << BK_LOG) | (dst & (BK_NODES-1)); bucket implied by position
__global__ __launch_bounds__(256) void k_bplace(const int* __restrict__ esrc,
                                                const int* __restrict__ edst,
                                                int* __restrict__ bcur,
                                                unsigned* __restrict__ pairs, int E) {
    __shared__ int2 sp[TILE_E];
    __shared__ int th[256], tx[256], rb[256], tmp[256];
    int t = threadIdx.x;
    th[t] = 0;
    __syncthreads();
    int base = blockIdx.x * TILE_E;
    int tot  = min(TILE_E, E - base);
#pragma unroll
    for (int k = 0; k < TILE_EPT; ++k) {
        int e = base + t + k * 256;
        if (e < E) atomicAdd(&th[edst[e] >> BK_LOG], 1);
    }
    __syncthreads();
    int cnt = th[t];
    tx[t] = scan256_excl(cnt, tmp);
    rb[t] = atomicAdd(&bcur[t], cnt);
    th[t] = 0;
    __syncthreads();
#pragma unroll
    for (int k = 0; k < TILE_EPT; ++k) {
        int e = base + t + k * 256;
        if (e < E) {
            int s = esrc[e], d = edst[e];
            int b = d >> BK_LOG;
            int r = atomicAdd(&th[b], 1);
            sp[tx[b] + r] = make_int2(s, d);
        }
    }
    __syncthreads();
    for (int i = t; i < tot; i += 256) {
        int2 p = sp[i];
        int  b = p.y >> BK_LOG;
        pairs[rb[b] + (i - tx[b])] =
            ((unsigned)p.x << BK_LOG) | (unsigned)(p.y & (BK_NODES - 1));
    }
}

// 512 threads: one bucket (512 nodes) per block, 1 node per thread
__global__ __launch_bounds__(512) void k_csr(const int* __restrict__ bbase,
                                             const unsigned* __restrict__ pairs,
                                             int* __restrict__ off,
                                             int* __restrict__ csr, int N) {
    __shared__ int lh[BK_NODES], lx[BK_NODES];
    int b = blockIdx.x, t = threadIdx.x;
    int lo = bbase[b], hi = bbase[b + 1];
    int node0 = b << BK_LOG;
    lh[t] = 0;
    __syncthreads();
    for (int j = lo + t; j < hi; j += 512)
        atomicAdd(&lh[pairs[j] & (BK_NODES - 1)], 1);
    __syncthreads();
    lx[t] = lh[t];
    __syncthreads();
    for (int d = 1; d < BK_NODES; d <<= 1) {
        int x0 = (t >= d) ? lx[t - d] : 0;
        __syncthreads();
        lx[t] += x0;
        __syncthreads();
    }
    lx[t] -= lh[t];
    if (node0 + t < N) off[node0 + t] = lo + lx[t];
    lh[t] = 0;
    __syncthreads();
    for (int j = lo + t; j < hi; j += 512) {
        unsigned p  = pairs[j];
        int      li = p & (BK_NODES - 1);
        int      r  = atomicAdd(&lh[li], 1);
        csr[lo + lx[li] + r] = (int)(p >> BK_LOG);
    }
}

// ---------------- aggregation + fused next-layer linear ----------------
// 8 lanes per node, float4 features per lane. Per-edge weight computed ONCE by
// the owning lane, broadcast via width-8 shuffle. Chunk loop software-pipelined:
// next chunk's csr + alpha loads issue before the current chunk's gather loop.
// Epilogue fuses the next 32x32 linear (W2 for layer 1 -> writes hpre2 +
// alpha2 dots; Wf+bf for layer 2 -> writes final out). Removes 2 dispatches
// and the 51 MB h round-trip between agg and gemm.
template <bool FINAL>
__global__ __launch_bounds__(256) void fused_agg(
    const int* __restrict__ csr, const int* __restrict__ off,
    const float* __restrict__ alpha_s, const float* __restrict__ alpha_d,
    const float* __restrict__ h, const float* __restrict__ bias,
    const float* __restrict__ Wn,            // next linear, 32x32 row-major
    const float* __restrict__ an_s, const float* __restrict__ an_d,
    const float* __restrict__ bn,            // FINAL: next bias
    float* __restrict__ outh,                // !FINAL: hpre_next; FINAL: out
    float* __restrict__ out_as, float* __restrict__ out_ad, int N)
{
    int t = blockIdx.x * 256 + threadIdx.x;
    int i = t >> 3, q = t & 7;          // node i, feature quad q (k = q*4..q*4+3)
    if (i >= N) return;
    int s0 = off[i], s1 = off[i + 1];
    float ad = alpha_d[i];

    const float* hq = h + q * 4;        // per-lane feature base

    // self loop
    float w   = __expf(leaky(alpha_s[i] + ad));
    float den = w;
    f32x4 hv  = *(const f32x4*)(hq + (size_t)i * 32);
    f32x4 acc;
    acc[0] = w * hv[0]; acc[1] = w * hv[1]; acc[2] = w * hv[2]; acc[3] = w * hv[3];

    // pipelined 32-edge chunks: lane q owns edges j+q+{0,8,16,24}
    int   c0 = 0, c1 = 0, c2 = 0, c3 = 0;
    float a0 = 0.f, a1 = 0.f, a2 = 0.f, a3 = 0.f;
    {
        int i0 = s0 + q;
        c0 = (i0      < s1) ? csr[i0]      : 0;
        c1 = (i0 + 8  < s1) ? csr[i0 + 8]  : 0;
        c2 = (i0 + 16 < s1) ? csr[i0 + 16] : 0;
        c3 = (i0 + 24 < s1) ? csr[i0 + 24] : 0;
        a0 = alpha_s[c0]; a1 = alpha_s[c1]; a2 = alpha_s[c2]; a3 = alpha_s[c3];
    }
    for (int j = s0; j < s1; j += 32) {
        // prefetch next chunk's csr indices (overlaps current gathers)
        int jn = j + 32;
        int n0 = 0, n1 = 0, n2 = 0, n3 = 0;
        if (jn < s1) {
            int i0 = jn + q;
            n0 = (i0      < s1) ? csr[i0]      : 0;
            n1 = (i0 + 8  < s1) ? csr[i0 + 8]  : 0;
            n2 = (i0 + 16 < s1) ? csr[i0 + 16] : 0;
            n3 = (i0 + 24 < s1) ? csr[i0 + 24] : 0;
        }
        int i0 = j + q;
        float w0 = (i0      < s1) ? __expf(leaky(a0 + ad)) : 0.0f;
        float w1 = (i0 + 8  < s1) ? __expf(leaky(a1 + ad)) : 0.0f;
        float w2 = (i0 + 16 < s1) ? __expf(leaky(a2 + ad)) : 0.0f;
        float w3 = (i0 + 24 < s1) ? __expf(leaky(a3 + ad)) : 0.0f;
        // prefetch next chunk's alpha values
        float na0 = alpha_s[n0], na1 = alpha_s[n1];
        float na2 = alpha_s[n2], na3 = alpha_s[n3];
        int o0 = c0 << 5, o1 = c1 << 5, o2 = c2 << 5, o3 = c3 << 5;
#pragma unroll
        for (int e = 0; e < 8; ++e) {
            int   e0 = __shfl(o0, e, 8); float f0 = __shfl(w0, e, 8);
            int   e1 = __shfl(o1, e, 8); float f1 = __shfl(w1, e, 8);
            int   e2 = __shfl(o2, e, 8); float f2 = __shfl(w2, e, 8);
            int   e3 = __shfl(o3, e, 8); float f3 = __shfl(w3, e, 8);
            f32x4 g0 = *(const f32x4*)(hq + e0);
            f32x4 g1 = *(const f32x4*)(hq + e1);
            f32x4 g2 = *(const f32x4*)(hq + e2);
            f32x4 g3 = *(const f32x4*)(hq + e3);
            den += (f0 + f1) + (f2 + f3);
            acc[0] += f0 * g0[0]; acc[1] += f0 * g0[1];
            acc[2] += f0 * g0[2]; acc[3] += f0 * g0[3];
            acc[0] += f1 * g1[0]; acc[1] += f1 * g1[1];
            acc[2] += f1 * g1[2]; acc[3] += f1 * g1[3];
            acc[0] += f2 * g2[0]; acc[1] += f2 * g2[1];
            acc[2] += f2 * g2[2]; acc[3] += f2 * g2[3];
            acc[0] += f3 * g3[0]; acc[1] += f3 * g3[1];
            acc[2] += f3 * g3[2]; acc[3] += f3 * g3[3];
        }
        c0 = n0; c1 = n1; c2 = n2; c3 = n3;
        a0 = na0; a1 = na1; a2 = na2; a3 = na3;
    }

    // this layer's output row quad (relu'd)
    float inv = 1.0f / den;
    f32x4 b4  = *(const f32x4*)(bias + q * 4);
    f32x4 r;
    r[0] = fmaxf(acc[0] * inv + b4[0], 0.0f);
    r[1] = fmaxf(acc[1] * inv + b4[1], 0.0f);
    r[2] = fmaxf(acc[2] * inv + b4[2], 0.0f);
    r[3] = fmaxf(acc[3] * inv + b4[3], 0.0f);

    // fused next-layer 32x32 linear: m[q*4+jj'] = sum_k row[k] * Wn[k][q*4+jj']
    f32x4 m = {0.f, 0.f, 0.f, 0.f};
#pragma unroll
    for (int e = 0; e < 8; ++e) {
        f32x4 rv;
        rv[0] = __shfl(r[0], e, 8);
        rv[1] = __shfl(r[1], e, 8);
        rv[2] = __shfl(r[2], e, 8);
        rv[3] = __shfl(r[3], e, 8);
#pragma unroll
        for (int jj = 0; jj < 4; ++jj) {
            f32x4 wr = *(const f32x4*)(Wn + (e * 4 + jj) * 32 + q * 4);
            m[0] += rv[jj] * wr[0]; m[1] += rv[jj] * wr[1];
            m[2] += rv[jj] * wr[2]; m[3] += rv[jj] * wr[3];
        }
    }

    if (FINAL) {
        f32x4 bb = *(const f32x4*)(bn + q * 4);
        m[0] += bb[0]; m[1] += bb[1]; m[2] += bb[2]; m[3] += bb[3];
        *(f32x4*)(outh + (size_t)i * 32 + q * 4) = m;
    } else {
        *(f32x4*)(outh + (size_t)i * 32 + q * 4) = m;
        // next-layer attention dots
        f32x4 as4 = *(const f32x4*)(an_s + q * 4);
        f32x4 ad4 = *(const f32x4*)(an_d + q * 4);
        float ps = m[0] * as4[0] + m[1] * as4[1] + m[2] * as4[2] + m[3] * as4[3];
        float pd = m[0] * ad4[0] + m[1] * ad4[1] + m[2] * ad4[2] + m[3] * ad4[3];
#pragma unroll
        for (int msk = 4; msk >= 1; msk >>= 1) {
            ps += __shfl_xor(ps, msk, 8);
            pd += __shfl_xor(pd, msk, 8);
        }
        if (q == 0) { out_as[i] = ps; out_ad[i] = pd; }
    }
}

extern "C" void kernel_launch(void* const* d_in, const int* in_sizes, int n_in,
                              void* d_out, int out_size, void* d_ws, size_t ws_size,
                              hipStream_t stream)
{
    const float* x   = (const float*)d_in[0];
    const int*   ei  = (const int*)d_in[1];
    const float* W1  = (const float*)d_in[2];
    const float* a1s = (const float*)d_in[3];
    const float* a1d = (const float*)d_in[4];
    const float* b1  = (const float*)d_in[5];
    const float* W2  = (const float*)d_in[6];
    const float* a2s = (const float*)d_in[7];
    const float* a2d = (const float*)d_in[8];
    const float* b2  = (const float*)d_in[9];
    const float* Wf  = (const float*)d_in[10];
    const float* bf  = (const float*)d_in[11];

    const int N = in_sizes[0] / 128;
    const int E = in_sizes[1] / 2;
    const int* esrc = ei;
    const int* edst = ei + E;
    const int B1 = (N + BK_NODES - 1) >> BK_LOG;

    // Workspace (4B units): h1 32N | h2 32N | alpha_s N | alpha_d N |
    //   alpha_s2 N | alpha_d2 N | off N+1 | csr E | bcnt 256 | bbase 257 |
    //   bcur 256 | wfrag arrays
    float* ws = (float*)d_ws;
    float* h1       = ws;
    float* h2       = h1 + (size_t)N * 32;
    float* alpha_s  = h2 + (size_t)N * 32;
    float* alpha_d  = alpha_s + N;
    float* alpha_s2 = alpha_d + N;
    float* alpha_d2 = alpha_s2 + N;
    int*   off      = (int*)(alpha_d2 + N);
    int*   csr      = off + (N + 1);
    int*   bcnt     = csr + E;
    int*   bbase    = bcnt + 256;
    int*   bcur     = bbase + 257;
    unsigned short* wfb =
        (unsigned short*)(((uintptr_t)(bcur + 256) + 15) & ~(uintptr_t)15);
    unsigned short* wh1 = wfb;            // 4096 each for K=128
    unsigned short* wl1 = wh1 + 4096;
    // pairs (E uint32, packed) aliases h2: gemm1 runs before bplace (writes
    // h1); h2 stays dead until agg1, which runs after k_csr.
    unsigned* pairs = ((size_t)E <= (size_t)32 * N)
                          ? (unsigned*)h2
                          : (unsigned*)(wl1 + 4096);

    const int nb_agg  = (N * 8 + 255) / 256;
    const int nb_tile = (E + TILE_E - 1) / TILE_E;
    const int nb_gemm = ((N + 15) / 16 + 3) / 4;

    // ---- prep: W1 fragments + bcnt zero (1 dispatch) ----
    k_prep<<<3, 256, 0, stream>>>(W1, wh1, wl1, bcnt);

    // ---- bucket count + layer-1 GEMM (independent; 1 dispatch) ----
    k_bcount_gemm1<<<nb_tile + nb_gemm, 256, 0, stream>>>(
        edst, bcnt, E, nb_tile, x, wh1, wl1, a1s, a1d, h1, alpha_s, alpha_d, N);

    // ---- CSR build ----
    k_bscan  <<<1, 256, 0, stream>>>(bcnt, bbase, bcur, off, N, E);
    k_bplace <<<nb_tile, 256, 0, stream>>>(esrc, edst, bcur, pairs, E);
    k_csr    <<<B1, 512, 0, stream>>>(bbase, pairs, off, csr, N);

    // ---- layer-1 aggregate + fused layer-2 linear/attention dots ----
    fused_agg<false><<<nb_agg, 256, 0, stream>>>(
        csr, off, alpha_s, alpha_d, h1, b1, W2, a2s, a2d, nullptr,
        h2, alpha_s2, alpha_d2, N);

    // ---- layer-2 aggregate + fused final linear ----
    fused_agg<true><<<nb_agg, 256, 0, stream>>>(
        csr, off, alpha_s2, alpha_d2, h2, b2, Wf, nullptr, nullptr, bf,
        (float*)d_out, nullptr, nullptr, N);
}